// Round 13
// baseline (110.704 us; speedup 1.0000x reference)
//
#include <hip/hip_runtime.h>

// B=32, C=8, L=2048, K=512, S=64, W=1985
// out[b,0,q] = max(0, max_w sum_c dot(xw_n[b,c,w,:], sn_n[c,q,:]) / 8)
//
// v14: wave de-phasing. v5..v13 falsified schedule/occupancy/feed-path/
// instr-ratio as the wall; the invariant is the CONVOY: identical waves
// stay phase-locked, so TA-burst and MFMA-burst alternate (pipes add,
// ~5k cyc/c-step) instead of overlapping (max ~2.5k). v14 = v8's
// persistent-LDS-B barrier-free structure + (a) Hankel dedup (6 A-frags
// + 2 iv = 8 VMEM/c, frag(mt,ks) = g[2mt+ks]) + (b) a runtime-keyed
// s_nop skew after the single barrier: co-resident blocks' same-wv waves
// (which share a SIMD) get different skews, so one wave's loads fly under
// its sibling's MFMA burst for the whole barrier-free loop. setprio kept
// (T5 pays only with role diversity -- the skew creates it).

#define B_ 32
#define C_ 8
#define L_ 2048
#define K_ 512
#define S_ 64
#define W_ 1985
#define XS_ 2176                      // padded f16 row stride (L_ + 128)

typedef _Float16 f16x8  __attribute__((ext_vector_type(8)));
typedef _Float16 f16x8u __attribute__((ext_vector_type(8), aligned(4)));
typedef float    f32x16 __attribute__((ext_vector_type(16)));

// ---- prologue (v3..v13 version, harness-verified) ----
__global__ __launch_bounds__(256)
void prep_k(const float* __restrict__ x, const float* __restrict__ sh,
            _Float16* __restrict__ Bp, float* __restrict__ invn,
            _Float16* __restrict__ xh0, _Float16* __restrict__ xh1,
            float* __restrict__ out) {
    __shared__ float xr[L_];
    const int tid = threadIdx.x;
    const int blk = blockIdx.x;

    if (blk < 128) {
        const int sb   = blk * 4 + (tid >> 6);   // 0..511 = c(8) x kq(4) x nt(16)
        const int c    = sb >> 6;
        const int kq   = (sb >> 4) & 3;
        const int nt   = sb & 15;
        const int lane = tid & 63;
        const int half = lane >> 5;
        const int q    = nt * 32 + (lane & 31);

        const float4* sp = (const float4*)(sh + (size_t)(c * K_ + q) * S_);
        float ss = 0.f;
        #pragma unroll
        for (int i = 0; i < 8; ++i) {
            float4 v = sp[half * 8 + i];
            ss += v.x * v.x + v.y * v.y + v.z * v.z + v.w * v.w;
        }
        ss += __shfl_xor(ss, 32);
        float inv = 1.f / fmaxf(sqrtf(ss), 1e-8f);

        float4 u0 = sp[kq * 4 + half * 2];
        float4 u1 = sp[kq * 4 + half * 2 + 1];
        f16x8 o;
        o[0] = (_Float16)(u0.x * inv); o[1] = (_Float16)(u0.y * inv);
        o[2] = (_Float16)(u0.z * inv); o[3] = (_Float16)(u0.w * inv);
        o[4] = (_Float16)(u1.x * inv); o[5] = (_Float16)(u1.y * inv);
        o[6] = (_Float16)(u1.z * inv); o[7] = (_Float16)(u1.w * inv);
        ((f16x8*)Bp)[((c * 4 + kq) * 16 + nt) * 64 + lane] = o;
    } else {
        const int r = blk - 128;                 // 0..255 = b*8+c
        const float* xp = x + (size_t)r * L_;
        for (int i = tid; i < L_ / 4; i += 256)
            ((float4*)xr)[i] = ((const float4*)xp)[i];
        __syncthreads();

        float* ivp = invn + (size_t)r * L_;
        const int w0 = tid * 8;
        float ss = 0.f;
        if (w0 < W_) {
            #pragma unroll
            for (int j = 0; j < S_; ++j) { float v = xr[w0 + j]; ss += v * v; }
        }
        #pragma unroll
        for (int u = 0; u < 8; ++u) {
            int w = w0 + u;
            float o = 0.f;
            if (u > 0 && w < W_)
                ss += xr[w + 63] * xr[w + 63] - xr[w - 1] * xr[w - 1];
            if (w < W_) o = 0.125f / fmaxf(sqrtf(ss), 1e-8f);
            if (w < L_) ivp[w] = o;
        }

        _Float16* p0 = xh0 + (size_t)r * XS_;
        _Float16* p1 = xh1 + (size_t)r * XS_;
        for (int i = tid; i < XS_ / 8; i += 256) {
            f16x8 o0, o1;
            #pragma unroll
            for (int j = 0; j < 8; ++j) {
                int e = i * 8 + j;
                o0[j] = (_Float16)((e     < L_) ? xr[e]     : 0.f);
                o1[j] = (_Float16)((e + 1 < L_) ? xr[e + 1] : 0.f);
            }
            ((f16x8*)p0)[i] = o0;
            ((f16x8*)p1)[i] = o1;
        }
        if (r < 64) out[r * 256 + tid] = 0.f;    // zero output
    }
}

// global -> LDS direct copy, 16B per lane (dest = uniform base + lane*16)
__device__ __forceinline__ void glds16(const void* g, void* l) {
    __builtin_amdgcn_global_load_lds(
        (const __attribute__((address_space(1))) unsigned int*)g,
        (__attribute__((address_space(3))) unsigned int*)l, 16, 0, 0);
}

// A: 6 distinct Hankel fragments + 2 inv-norms (8 VMEM), NAMED buffers.
// g[p] covers window-row offset p*16; frag(mt,ks) = g[2mt + ks].
__device__ __forceinline__ void loadA(
    int c, const _Float16* __restrict__ xbase, const float* __restrict__ ivbase,
    int m0, int m1, f16x8 (&g)[6], float (&iv)[2])
{
    iv[0] = ivbase[(size_t)c * L_ + m0];         // 0 for invalid windows
    iv[1] = ivbase[(size_t)c * L_ + m1];
    const _Float16* xp = xbase + (size_t)c * XS_;
    #pragma unroll
    for (int p = 0; p < 6; ++p)
        g[p] = *(const f16x8u*)(xp + p * 16);
}

// 8 ds_read_b128 (persistent B panel) + scale A + 16 MFMAs
__device__ __forceinline__ void compC(
    int c, const f16x8* __restrict__ bsl, int lane,
    const f16x8 (&g)[6], const float (&iv)[2], f32x16 (&acc)[2][2])
{
    f16x8 bf[8];
    #pragma unroll
    for (int ks = 0; ks < 4; ++ks)
        #pragma unroll
        for (int nt = 0; nt < 2; ++nt)
            bf[ks * 2 + nt] = bsl[(c * 8 + ks * 2 + nt) * 64 + lane];

    const _Float16 h0 = (_Float16)iv[0], h1 = (_Float16)iv[1];
    f16x8 is0, is1;
    #pragma unroll
    for (int j = 0; j < 8; ++j) { is0[j] = h0; is1[j] = h1; }

    __builtin_amdgcn_s_setprio(1);
    #pragma unroll
    for (int ks = 0; ks < 4; ++ks) {
        f16x8 a0 = g[ks]     * is0;              // frag(mt=0,ks) = g[ks]
        f16x8 a1 = g[ks + 2] * is1;              // frag(mt=1,ks) = g[ks+2]
        #pragma unroll
        for (int nt = 0; nt < 2; ++nt) {
            acc[0][nt] = __builtin_amdgcn_mfma_f32_32x32x16_f16(
                a0, bf[ks * 2 + nt], acc[0][nt], 0, 0, 0);
            acc[1][nt] = __builtin_amdgcn_mfma_f32_32x32x16_f16(
                a1, bf[ks * 2 + nt], acc[1][nt], 0, 0, 0);
        }
    }
    __builtin_amdgcn_s_setprio(0);
}

// ---- main: persistent-LDS B, single barrier, de-phased free-running loop ----
// grid (8 wt, 8 ng, 32 b) = 2048 blocks, 4 waves. Wave: 64 windows (2x32)
// x 64 q (2x32); acc = 4 x f32x16. After the one staging barrier, each wave
// runs a keyed s_nop skew (0..~1300cy) so SIMD-sibling waves (same wv,
// different co-resident block) de-phase: loads overlap sibling MFMA bursts.
__global__ __launch_bounds__(256, 2)
void mcs_k(const _Float16* __restrict__ xh0, const _Float16* __restrict__ xh1,
           const _Float16* __restrict__ Bp, const float* __restrict__ invn,
           float* __restrict__ out) {
    const int wt  = blockIdx.x;           // 0..7  256-window tile
    const int ng  = blockIdx.y;           // 0..7  64-q panel
    const int b   = blockIdx.z;
    const int tid = threadIdx.x;
    const int lane = tid & 63;
    const int wv   = tid >> 6;            // window subgroup 0..3

    const int l31 = lane & 31;
    const int lh  = lane >> 5;
    const int Wb  = wt * 256 + wv * 64;   // wave window base
    const int m0  = Wb + l31;
    const int m1  = Wb + 32 + l31;

    __shared__ __attribute__((aligned(16))) f16x8 Bs[64][64];   // 64 KB

    // ---- stage B-panel once: wave wv stages units e = wv*16..+15 ----
    {
        const f16x8* bp = (const f16x8*)Bp;
        #pragma unroll
        for (int u = 0; u < 16; ++u) {
            const int e   = wv * 16 + u;
            const int c   = e >> 3;
            const int sub = e & 7;                    // ks*2 + nt
            const int src = ((c * 4 + (sub >> 1)) * 16 + ng * 2 + (sub & 1)) * 64;
            glds16(bp + src + lane, &Bs[e][0]);
        }
    }

    // parity-selected x base keeps every f16x8 load 4B-aligned
    const _Float16* xb = (l31 & 1) ? (xh1 - 1) : xh0;
    const _Float16* xbase = xb + (size_t)b * C_ * XS_ + Wb + l31 + lh * 8;
    const float*   ivbase = invn + (size_t)b * C_ * L_;
    const f16x8*   Bsl = &Bs[0][0];

    f32x16 acc[2][2];
    #pragma unroll
    for (int mt = 0; mt < 2; ++mt)
        #pragma unroll
        for (int nt = 0; nt < 2; ++nt)
            #pragma unroll
            for (int r = 0; r < 16; ++r) acc[mt][nt][r] = 0.f;

    f16x8 gA[6], gB[6];
    float ivA[2], ivB[2];

    loadA(0, xbase, ivbase, m0, m1, gA, ivA);   // overlaps the staging
    __syncthreads();                            // B-panel ready (vmcnt drained)

    // ---- de-phase: keyed skew, survives the whole barrier-free loop ----
    {
        const int key = (wt + ng * 3 + b * 5 + wv) & 3;
        const int n   = key * 48;                // 0..144 x ~9cy ~= 0..1300cy
        #pragma unroll 1
        for (int i = 0; i < n; ++i) asm volatile("s_nop 7");
    }

    #pragma unroll 1
    for (int cp = 0; cp < 4; ++cp) {
        const int c0 = cp * 2;
        loadA(c0 + 1, xbase, ivbase, m0, m1, gB, ivB);
        compC(c0, Bsl, lane, gA, ivA, acc);
        if (cp < 3)
            loadA(c0 + 2, xbase, ivbase, m0, m1, gA, ivA);
        compC(c0 + 1, Bsl, lane, gB, ivB, acc);
    }

    // epilogue: relu + max over windows; col(q) = lane&31; fold lane^32;
    // waves cover disjoint windows -> atomicMax combines (values >= 0).
    #pragma unroll
    for (int nt = 0; nt < 2; ++nt) {
        float v = 0.f;
        #pragma unroll
        for (int mt = 0; mt < 2; ++mt)
            #pragma unroll
            for (int r = 0; r < 16; ++r) v = fmaxf(v, acc[mt][nt][r]);
        v = fmaxf(v, __shfl_xor(v, 32));
        if (lane < 32)
            atomicMax((unsigned int*)(out + (size_t)b * K_ + ng * 64 + nt * 32 + l31),
                      __float_as_uint(v));
    }
}

extern "C" void kernel_launch(void* const* d_in, const int* in_sizes, int n_in,
                              void* d_out, int out_size, void* d_ws, size_t ws_size,
                              hipStream_t stream) {
    const float* x  = (const float*)d_in[0];   // (32, 8, 2048) fp32
    const float* sh = (const float*)d_in[1];   // (8, 512, 64) fp32
    float* out = (float*)d_out;                // (32, 1, 512) fp32

    // workspace: Bp 512KB | invn 2MB | xh0 ~1.06MB | xh1 ~1.06MB (~4.7MB
    // dirty footprint -- keeps the harness's 256MiB re-poison fill fast)
    _Float16* Bp   = (_Float16*)d_ws;
    float*    invn = (float*)((char*)d_ws + (512 << 10));
    _Float16* xh0  = (_Float16*)((char*)d_ws + (512 << 10) + (2 << 20));
    _Float16* xh1  = xh0 + (size_t)B_ * C_ * XS_;

    prep_k<<<dim3(384), dim3(256), 0, stream>>>(x, sh, Bp, invn, xh0, xh1, out);
    mcs_k<<<dim3(8, 8, B_), dim3(256), 0, stream>>>(xh0, xh1, Bp, invn, out);
}

// Round 14
// 94.651 us; speedup vs baseline: 1.1696x; 1.1696x over previous
//
#include <hip/hip_runtime.h>

// B=32, C=8, L=2048, K=512, S=64, W=1985
// out[b,0,q] = max(0, max_w sum_c dot(xw_n[b,c,w,:], sn_n[c,q,:]) / 8)
//
// v15 = v13 (session best, 94.7us) + packed inv-norm pairs.
// v13's feed-ratio lever was the only one of six structural levers that
// moved the ~46us mcs wall (schedule, occupancy, feed-path, de-phasing all
// null/negative). v15 shaves the last redundant feed instructions: invn is
// stored as interleaved (iv[T*64+s], iv[T*64+32+s]) float pairs so each
// wave's two per-c inv-norms arrive in ONE global_load_dwordx2 instead of
// two scalar loads: 8 -> 7 VMEM per 32 MFMAs per wave-c. f32 precision,
// zero numerics change. Everything else is v13 verbatim.

#define B_ 32
#define C_ 8
#define L_ 2048
#define K_ 512
#define S_ 64
#define W_ 1985
#define XS_ 2176                      // padded f16 row stride (L_ + 128)

typedef _Float16 f16x8  __attribute__((ext_vector_type(8)));
typedef _Float16 f16x8u __attribute__((ext_vector_type(8), aligned(4)));
typedef float    f32x16 __attribute__((ext_vector_type(16)));

// ---- prologue ----
// blocks 0..127: pack shapelets in 32x32x16 frag layout (unchanged).
// blocks 128..383: per (b,c): f16 dual-parity x copies + PACKED inv-norm
//   pairs: ivp2[T*32 + s] = (iv[T*64+s], iv[T*64+32+s]), s in 0..31.
__global__ __launch_bounds__(256)
void prep_k(const float* __restrict__ x, const float* __restrict__ sh,
            _Float16* __restrict__ Bp, float* __restrict__ invn,
            _Float16* __restrict__ xh0, _Float16* __restrict__ xh1,
            float* __restrict__ out) {
    __shared__ float xr[L_];
    const int tid = threadIdx.x;
    const int blk = blockIdx.x;

    if (blk < 128) {
        const int sb   = blk * 4 + (tid >> 6);   // 0..511 = c(8) x kq(4) x nt(16)
        const int c    = sb >> 6;
        const int kq   = (sb >> 4) & 3;
        const int nt   = sb & 15;
        const int lane = tid & 63;
        const int half = lane >> 5;
        const int q    = nt * 32 + (lane & 31);

        const float4* sp = (const float4*)(sh + (size_t)(c * K_ + q) * S_);
        float ss = 0.f;
        #pragma unroll
        for (int i = 0; i < 8; ++i) {
            float4 v = sp[half * 8 + i];
            ss += v.x * v.x + v.y * v.y + v.z * v.z + v.w * v.w;
        }
        ss += __shfl_xor(ss, 32);
        float inv = 1.f / fmaxf(sqrtf(ss), 1e-8f);

        float4 u0 = sp[kq * 4 + half * 2];
        float4 u1 = sp[kq * 4 + half * 2 + 1];
        f16x8 o;
        o[0] = (_Float16)(u0.x * inv); o[1] = (_Float16)(u0.y * inv);
        o[2] = (_Float16)(u0.z * inv); o[3] = (_Float16)(u0.w * inv);
        o[4] = (_Float16)(u1.x * inv); o[5] = (_Float16)(u1.y * inv);
        o[6] = (_Float16)(u1.z * inv); o[7] = (_Float16)(u1.w * inv);
        ((f16x8*)Bp)[((c * 4 + kq) * 16 + nt) * 64 + lane] = o;
    } else {
        const int r = blk - 128;                 // 0..255 = b*8+c
        const float* xp = x + (size_t)r * L_;
        for (int i = tid; i < L_ / 4; i += 256)
            ((float4*)xr)[i] = ((const float4*)xp)[i];
        __syncthreads();

        // packed iv pairs: row stride 2048 floats (1024 float2)
        float* ivp = invn + (size_t)r * 2048;
        const int w0 = tid * 8;
        float ss = 0.f;
        if (w0 < W_) {
            #pragma unroll
            for (int j = 0; j < S_; ++j) { float v = xr[w0 + j]; ss += v * v; }
        }
        #pragma unroll
        for (int u = 0; u < 8; ++u) {
            int w = w0 + u;
            float o = 0.f;
            if (u > 0 && w < W_)
                ss += xr[w + 63] * xr[w + 63] - xr[w - 1] * xr[w - 1];
            if (w < W_) o = 0.125f / fmaxf(sqrtf(ss), 1e-8f);
            if (w < L_) {
                const int T = w >> 6, s = w & 63;
                ivp[(T * 32 + (s & 31)) * 2 + (s >> 5)] = o;
            }
        }

        _Float16* p0 = xh0 + (size_t)r * XS_;
        _Float16* p1 = xh1 + (size_t)r * XS_;
        for (int i = tid; i < XS_ / 8; i += 256) {
            f16x8 o0, o1;
            #pragma unroll
            for (int j = 0; j < 8; ++j) {
                int e = i * 8 + j;
                o0[j] = (_Float16)((e     < L_) ? xr[e]     : 0.f);
                o1[j] = (_Float16)((e + 1 < L_) ? xr[e + 1] : 0.f);
            }
            ((f16x8*)p0)[i] = o0;
            ((f16x8*)p1)[i] = o1;
        }
        if (r < 64) out[r * 256 + tid] = 0.f;    // zero output
    }
}

// global -> LDS direct copy, 16B per lane (dest = uniform base + lane*16)
__device__ __forceinline__ void glds16(const void* g, void* l) {
    __builtin_amdgcn_global_load_lds(
        (const __attribute__((address_space(1))) unsigned int*)g,
        (__attribute__((address_space(3))) unsigned int*)l, 16, 0, 0);
}

// A: 6 distinct Hankel fragments + 1 packed iv pair (7 VMEM).
// g[p] covers window-row offset p*16; frag(mt,ks) = g[2mt + ks].
__device__ __forceinline__ void loadA(
    int c, const _Float16* __restrict__ xbase, const float* __restrict__ ivbase,
    int ivoff, f16x8 (&g)[6], float (&iv)[2])
{
    const float2 p = *(const float2*)(ivbase + (size_t)c * 2048 + ivoff * 2);
    iv[0] = p.x;                                 // window m0 (0 if invalid)
    iv[1] = p.y;                                 // window m0+32
    const _Float16* xp = xbase + (size_t)c * XS_;
    #pragma unroll
    for (int q = 0; q < 6; ++q)
        g[q] = *(const f16x8u*)(xp + q * 16);
}

// one channel: 16 ds_read_b128 (B frag consumed immediately by the (a0,a1)
// MFMA pair -> ~2 live bf regs) + 32 MFMAs. cc = c & 3.
__device__ __forceinline__ void compC(
    int cc, const f16x8* __restrict__ Bsl, int lane,
    const f16x8 (&g)[6], const float (&iv)[2], f32x16 (&acc)[2][4])
{
    const _Float16 h0 = (_Float16)iv[0], h1 = (_Float16)iv[1];
    f16x8 is0, is1;
    #pragma unroll
    for (int j = 0; j < 8; ++j) { is0[j] = h0; is1[j] = h1; }

    #pragma unroll
    for (int ks = 0; ks < 4; ++ks) {
        f16x8 a0 = g[ks]     * is0;              // frag(mt=0,ks) = g[ks]
        f16x8 a1 = g[ks + 2] * is1;              // frag(mt=1,ks) = g[ks+2]
        #pragma unroll
        for (int nt = 0; nt < 4; ++nt) {
            f16x8 bf = Bsl[((cc * 4 + ks) * 4 + nt) * 64 + lane];
            acc[0][nt] = __builtin_amdgcn_mfma_f32_32x32x16_f16(
                a0, bf, acc[0][nt], 0, 0, 0);
            acc[1][nt] = __builtin_amdgcn_mfma_f32_32x32x16_f16(
                a1, bf, acc[1][nt], 0, 0, 0);
        }
    }
}

// ---- main: 2-phase persistent-LDS B (4 c x 128 q per phase) ----
// grid (8 wt, 4 ng, 32 b) = 1024 blocks, 4 waves. Wave: 64 windows (2x32)
// x 128 q (4x32); acc = 8 x f32x16 = 128 regs. Phase p: stage 64KB B-panel
// for c = p*4..p*4+3 (16 glds16/wave), barrier, then 4 barrier-free c-steps
// with A reg-prefetch (6 Hankel frags + 1 iv-pair = 7 VMEM per 32 MFMAs).
__global__ __launch_bounds__(256, 2)
void mcs_k(const _Float16* __restrict__ xh0, const _Float16* __restrict__ xh1,
           const _Float16* __restrict__ Bp, const float* __restrict__ invn,
           float* __restrict__ out) {
    const int wt  = blockIdx.x;           // 0..7  256-window tile
    const int ng  = blockIdx.y;           // 0..3  128-q panel
    const int b   = blockIdx.z;
    const int tid = threadIdx.x;
    const int lane = tid & 63;
    const int wv   = tid >> 6;            // window subgroup 0..3

    const int l31 = lane & 31;
    const int lh  = lane >> 5;
    const int Wb  = wt * 256 + wv * 64;   // wave window base
    const int ivoff = (Wb >> 1) + l31;    // packed iv-pair index

    __shared__ __attribute__((aligned(16))) f16x8 Bs[64][64];   // 64 KB/phase

    // parity-selected x base keeps every f16x8 load 4B-aligned
    const _Float16* xb = (l31 & 1) ? (xh1 - 1) : xh0;
    const _Float16* xbase = xb + (size_t)b * C_ * XS_ + Wb + l31 + lh * 8;
    const float*   ivbase = invn + (size_t)b * C_ * 2048;
    const f16x8*   Bsl = &Bs[0][0];
    const f16x8*   bp  = (const f16x8*)Bp;

    f32x16 acc[2][4];
    #pragma unroll
    for (int mt = 0; mt < 2; ++mt)
        #pragma unroll
        for (int nt = 0; nt < 4; ++nt)
            #pragma unroll
            for (int r = 0; r < 16; ++r) acc[mt][nt][r] = 0.f;

    f16x8 gE[6], gO[6];
    float ivE[2], ivO[2];

    // stage phase p's B-panel: unit e = cc*16 + ks*4 + nt  (cc = c&3)
    #define STAGE(p)                                                    \
        { _Pragma("unroll")                                             \
          for (int u = 0; u < 16; ++u) {                                \
              const int e  = wv * 16 + u;                               \
              const int cc = e >> 4, ks = (e >> 2) & 3, nt = e & 3;     \
              const int src = ((((p) * 4 + cc) * 4 + ks) * 16           \
                               + ng * 4 + nt) * 64;                     \
              glds16(bp + src + lane, &Bs[e][0]);                       \
          } }

    #pragma unroll 1
    for (int p = 0; p < 2; ++p) {
        const int c0 = p * 4;
        if (p) __syncthreads();           // all waves done reading phase 0
        STAGE(p);
        loadA(c0 + 0, xbase, ivbase, ivoff, gE, ivE);
        loadA(c0 + 1, xbase, ivbase, ivoff, gO, ivO);
        __syncthreads();                  // panel ready (vmcnt drained)

        compC(0, Bsl, lane, gE, ivE, acc);
        loadA(c0 + 2, xbase, ivbase, ivoff, gE, ivE);
        compC(1, Bsl, lane, gO, ivO, acc);
        loadA(c0 + 3, xbase, ivbase, ivoff, gO, ivO);
        compC(2, Bsl, lane, gE, ivE, acc);
        compC(3, Bsl, lane, gO, ivO, acc);
    }
    #undef STAGE

    // epilogue: relu + max over windows; C/D col(q) = lane&31, rows =
    // windows; fold lane^32 (same q), waves cover disjoint windows ->
    // atomicMax combines (values >= 0, uint compare valid).
    #pragma unroll
    for (int nt = 0; nt < 4; ++nt) {
        float v = 0.f;
        #pragma unroll
        for (int mt = 0; mt < 2; ++mt)
            #pragma unroll
            for (int r = 0; r < 16; ++r) v = fmaxf(v, acc[mt][nt][r]);
        v = fmaxf(v, __shfl_xor(v, 32));
        if (lane < 32)
            atomicMax((unsigned int*)(out + (size_t)b * K_ + ng * 128 + nt * 32 + l31),
                      __float_as_uint(v));
    }
}

extern "C" void kernel_launch(void* const* d_in, const int* in_sizes, int n_in,
                              void* d_out, int out_size, void* d_ws, size_t ws_size,
                              hipStream_t stream) {
    const float* x  = (const float*)d_in[0];   // (32, 8, 2048) fp32
    const float* sh = (const float*)d_in[1];   // (8, 512, 64) fp32
    float* out = (float*)d_out;                // (32, 1, 512) fp32

    // workspace: Bp 512KB | invn 2MB (packed pairs) | xh0 | xh1 (~4.7MB
    // dirty footprint -- keeps the harness's 256MiB re-poison fill fast)
    _Float16* Bp   = (_Float16*)d_ws;
    float*    invn = (float*)((char*)d_ws + (512 << 10));
    _Float16* xh0  = (_Float16*)((char*)d_ws + (512 << 10) + (2 << 20));
    _Float16* xh1  = xh0 + (size_t)B_ * C_ * XS_;

    prep_k<<<dim3(384), dim3(256), 0, stream>>>(x, sh, Bp, invn, xh0, xh1, out);
    mcs_k<<<dim3(8, 4, B_), dim3(256), 0, stream>>>(xh0, xh1, Bp, invn, out);
}